// Round 15
// baseline (344.849 us; speedup 1.0000x reference)
//
#include <hip/hip_runtime.h>
#include <stdint.h>

typedef float f32x4v __attribute__((ext_vector_type(4)));
typedef short short8v __attribute__((ext_vector_type(8)));

__device__ __forceinline__ float bf2f(unsigned short u) {
  union { uint32_t i; float f; } v; v.i = ((uint32_t)u) << 16; return v.f;
}
__device__ __forceinline__ unsigned short f2bf(float f) {
  union { float f; uint32_t i; } v; v.f = f;
  uint32_t x = v.i;
  uint32_t r = (x + 0x7FFFu + ((x >> 16) & 1u)) >> 16;
  return (unsigned short)r;
}
__device__ __forceinline__ short8v cvt8(float4 a, float4 b) {
  short8v v;
  v[0] = (short)f2bf(a.x); v[1] = (short)f2bf(a.y);
  v[2] = (short)f2bf(a.z); v[3] = (short)f2bf(a.w);
  v[4] = (short)f2bf(b.x); v[5] = (short)f2bf(b.y);
  v[6] = (short)f2bf(b.z); v[7] = (short)f2bf(b.w);
  return v;
}

// ---------------- zero count ----------------
__global__ void zero_kernel(int* __restrict__ p, int n4) {
  int i = blockIdx.x * blockDim.x + threadIdx.x;
  int stride = gridDim.x * blockDim.x;
  for (; i < n4; i += stride) ((int4*)p)[i] = make_int4(0, 0, 0, 0);
}

// ---------------- setup: prep weights + geometry + edge counts ----------------
__global__ void setup_kernel(const float* __restrict__ W1, const float* __restrict__ W2,
                             const float* __restrict__ points, const int* __restrict__ tri,
                             const int* __restrict__ te,
                             unsigned short* __restrict__ W1fT, unsigned short* __restrict__ W2T,
                             float* __restrict__ geo12, int* __restrict__ count,
                             int T, int E) {
  int i = blockIdx.x * blockDim.x + threadIdx.x;
  if (i < 256 * 288) {
    int n = i / 288, k = i % 288;
    float v = 0.f;
    if (k < 256) v = W1[(9 + k) * 256 + n];
    else if (k < 265) v = W1[(k - 256) * 256 + n];
    W1fT[i] = f2bf(v);
  }
  if (i < 256 * 256) {
    int n = i >> 8, k = i & 255;
    W2T[i] = f2bf(W2[k * 256 + n]);
  }
  if (i < T) {
    int t = i;
    int i0 = tri[3 * t], i1 = tri[3 * t + 1], i2 = tri[3 * t + 2];
    float g[12];
#pragma unroll
    for (int c = 0; c < 3; ++c) {
      float p0 = points[i0 * 3 + c], p1 = points[i1 * 3 + c], p2 = points[i2 * 3 + c];
      float e0 = p0 - p1, e1 = p0 - p2, e2 = p1 - p2;
      float mx = fmaxf(e0, fmaxf(e1, e2));
      float mn = fminf(e0, fminf(e1, e2));
      float bc = (p0 + p1 + p2) * (1.0f / 3.0f);
      g[c] = mn; g[3 + c] = mx; g[6 + c] = bc;
    }
    g[9] = 0.f; g[10] = 0.f; g[11] = 0.f;
    float4* o = (float4*)(geo12 + (size_t)t * 12);
    o[0] = make_float4(g[0], g[1], g[2], g[3]);
    o[1] = make_float4(g[4], g[5], g[6], g[7]);
    o[2] = make_float4(g[8], g[9], g[10], g[11]);
  }
  if (i < E) atomicAdd(&count[te[i]], 1);
}

// ---------------- CSR scan ----------------
__global__ void scan1_kernel(const int* __restrict__ count, int* __restrict__ incl,
                             int* __restrict__ blocksum, int T) {
  __shared__ int wsums[4];
  int tid = threadIdx.x, wave = tid >> 6, lane = tid & 63;
  int idx0 = blockIdx.x * 1024 + tid * 4;
  int c0 = 0, c1 = 0, c2 = 0, c3 = 0;
  if (idx0 + 3 < T) {
    int4 v = *(const int4*)(count + idx0);
    c0 = v.x; c1 = v.y; c2 = v.z; c3 = v.w;
  } else {
    if (idx0 < T) c0 = count[idx0];
    if (idx0 + 1 < T) c1 = count[idx0 + 1];
    if (idx0 + 2 < T) c2 = count[idx0 + 2];
  }
  int s = c0 + c1 + c2 + c3;
  int inclv = s;
#pragma unroll
  for (int off = 1; off < 64; off <<= 1) {
    int n = __shfl_up(inclv, off);
    if (lane >= off) inclv += n;
  }
  if (lane == 63) wsums[wave] = inclv;
  __syncthreads();
  int wbase = 0;
#pragma unroll
  for (int w = 0; w < 4; ++w) if (w < wave) wbase += wsums[w];
  int base = wbase + inclv - s;
  int e0 = base + c0, e1 = e0 + c1, e2 = e1 + c2, e3 = e2 + c3;
  if (idx0 < T) incl[idx0] = e0;
  if (idx0 + 1 < T) incl[idx0 + 1] = e1;
  if (idx0 + 2 < T) incl[idx0 + 2] = e2;
  if (idx0 + 3 < T) incl[idx0 + 3] = e3;
  if (tid == 255) blocksum[blockIdx.x] = wbase + inclv;
}

__global__ void scan2_kernel(const int* __restrict__ blocksum, int* __restrict__ blockbase, int nb) {
  __shared__ int wsums[4];
  int tid = threadIdx.x, wave = tid >> 6, lane = tid & 63;
  int v = (tid < nb) ? blocksum[tid] : 0;
  int inclv = v;
#pragma unroll
  for (int off = 1; off < 64; off <<= 1) {
    int n = __shfl_up(inclv, off);
    if (lane >= off) inclv += n;
  }
  if (lane == 63) wsums[wave] = inclv;
  __syncthreads();
  int wbase = 0;
#pragma unroll
  for (int w = 0; w < 4; ++w) if (w < wave) wbase += wsums[w];
  if (tid < nb) blockbase[tid] = wbase + inclv - v;
}

__global__ void scan3_kernel(const int* __restrict__ count, const int* __restrict__ incl,
                             const int* __restrict__ blockbase, int* __restrict__ offsets,
                             int* __restrict__ cursor, int T) {
  int idx = blockIdx.x * 1024 + threadIdx.x * 4;
  int bb = blockbase[blockIdx.x];
#pragma unroll
  for (int j = 0; j < 4; ++j) {
    int i = idx + j;
    if (i < T) {
      int o = incl[i] + bb;
      offsets[i + 1] = o;
      cursor[i] = o - count[i];
    }
  }
  if (blockIdx.x == 0 && threadIdx.x == 0) offsets[0] = 0;
}

__global__ void fill_kernel(const int* __restrict__ te, int* __restrict__ cursor,
                            int* __restrict__ tgt_list, int E) {
  int e = blockIdx.x * blockDim.x + threadIdx.x;
  if (e < E) {
    int s = te[e];
    int pos = atomicAdd(&cursor[s], 1);
    tgt_list[pos] = te[E + e];
  }
}

// ------- U = [x | geo] @ W1: N-split halves, 512 thr, B-half (72KB) in LDS, ------
// ------- XOR-swizzled, ring-4 A-prefetch, zero barriers in K-loop.         ------
// 2 blocks/CU co-resident -> staging of one block overlaps drain of the other.
__launch_bounds__(512, 4)
__global__ void ugemm_kernel(const float* __restrict__ x, const float* __restrict__ geo12,
                             const unsigned short* __restrict__ W1fT,
                             unsigned short* __restrict__ U, int T) {
  __shared__ alignas(16) unsigned short Bl[36864];  // 128 rows x 288 shorts = 72 KB
  int tid = threadIdx.x;
  int half = blockIdx.x & 1;
  int nbase = half * 128;
#pragma unroll
  for (int j = 0; j < 9; ++j) {
    int idx = tid + j * 512;
    int n = idx / 36, c = idx % 36;  // n = local row 0..127
    int pc = (c < 32) ? (c ^ (n & 7)) : (32 + ((c - 32) ^ (n & 3)));
    short8v v = *(const short8v*)(W1fT + (size_t)(nbase + n) * 288 + c * 8);
    *(short8v*)(&Bl[n * 288 + pc * 8]) = v;
  }
  __syncthreads();
  int wid = tid >> 6, lane = tid & 63;
  int l15 = lane & 15, lhi = lane >> 4;
  int r7 = l15 & 7, r3 = l15 & 3;
  const unsigned short* lane_b = &Bl[l15 * 288];
  int strip = (blockIdx.x >> 1) * 8 + wid;
  if (strip * 16 >= T) return;
  int row = strip * 16 + l15;
  const float* xrow = x + (size_t)row * 256 + 8 * lhi;
  float4 ga = make_float4(0, 0, 0, 0), gb = make_float4(0, 0, 0, 0);
  if (lhi < 2) {
    const float* gp = geo12 + (size_t)row * 12 + lhi * 8;
    ga = *(const float4*)gp;
    gb = *(const float4*)(gp + 4);
  }
  float4 pa[4], pb[4];
#pragma unroll
  for (int k = 0; k < 4; ++k) {
    pa[k] = *(const float4*)(xrow + k * 32);
    pb[k] = *(const float4*)(xrow + k * 32 + 4);
  }
  f32x4v acc[8] = {};
#pragma unroll
  for (int kk = 0; kk < 8; ++kk) {
    float4 ca = pa[kk & 3], cb = pb[kk & 3];
    if (kk < 4) {
      pa[kk & 3] = *(const float4*)(xrow + (kk + 4) * 32);
      pb[kk & 3] = *(const float4*)(xrow + (kk + 4) * 32 + 4);
    }
    short8v av = cvt8(ca, cb);
    int pc = (kk * 4 + lhi) ^ r7;
    const unsigned short* bptr = lane_b + pc * 8;
#pragma unroll
    for (int nf = 0; nf < 8; ++nf) {
      short8v bv = *(const short8v*)(bptr + nf * 4608);  // 16 rows * 288
      acc[nf] = __builtin_amdgcn_mfma_f32_16x16x32_bf16(av, bv, acc[nf], 0, 0, 0);
    }
  }
  {  // geo tail k=256..287
    short8v av = cvt8(ga, gb);
    int pc = 32 + (lhi ^ r3);
    const unsigned short* bptr = lane_b + pc * 8;
#pragma unroll
    for (int nf = 0; nf < 8; ++nf) {
      short8v bv = *(const short8v*)(bptr + nf * 4608);
      acc[nf] = __builtin_amdgcn_mfma_f32_16x16x32_bf16(av, bv, acc[nf], 0, 0, 0);
    }
  }
#pragma unroll
  for (int i = 0; i < 4; ++i) {
    int m = strip * 16 + 4 * lhi + i;
    unsigned short* urow = U + (size_t)m * 256 + nbase + l15;
#pragma unroll
    for (int nf = 0; nf < 8; ++nf)
      urow[nf * 16] = f2bf(acc[nf][i]);
  }
}

// ---------------- gather: sum_h[t] = sum_e relu(U[t]+b1-U[tgt]) ----------------
// (256,4): 44 VGPR, 8 in-flight 16B loads. Do NOT cap below 4 waves/EU (r3/r13).
__launch_bounds__(256, 4)
__global__ void gather_kernel(const unsigned short* __restrict__ U,
                              const int* __restrict__ offsets,
                              const int* __restrict__ tgt_list,
                              const float* __restrict__ b1,
                              unsigned short* __restrict__ sum_h, int T) {
  int gid = blockIdx.x * blockDim.x + threadIdx.x;
  int half = (T + 1) >> 1;
  int pair = gid >> 5;
  if (pair >= half) return;
  int c8 = (gid & 31) * 8;
  int tA = pair, tB = pair + half;
  bool hasRowB = tB < T;
  int begA = offsets[tA], endA = offsets[tA + 1];
  int begB = hasRowB ? offsets[tB] : 0, endB = hasRowB ? offsets[tB + 1] : 0;
  float b1r[8];
  {
    float4 a = *(const float4*)(b1 + c8);
    float4 b = *(const float4*)(b1 + c8 + 4);
    b1r[0] = a.x; b1r[1] = a.y; b1r[2] = a.z; b1r[3] = a.w;
    b1r[4] = b.x; b1r[5] = b.y; b1r[6] = b.z; b1r[7] = b.w;
  }
  short8v uva = *(const short8v*)(U + (size_t)tA * 256 + c8);
  short8v uvb = *(const short8v*)(U + (size_t)(hasRowB ? tB : tA) * 256 + c8);
  float uA[8], sA[8], uB[8], sB[8];
#pragma unroll
  for (int j = 0; j < 8; ++j) {
    uA[j] = bf2f((unsigned short)uva[j]) + b1r[j]; sA[j] = 0.f;
    uB[j] = bf2f((unsigned short)uvb[j]) + b1r[j]; sB[j] = 0.f;
  }
  int eiA = begA, eiB = begB;
  while (eiA < endA || eiB < endB) {
    bool hasA = eiA < endA, hasB = eiB < endB;
    int laA = hasA ? endA - 1 : 0;
    int laB = hasB ? endB - 1 : 0;
    int a0 = hasA ? eiA : 0;
    int a1 = hasA ? min(eiA + 1, laA) : 0;
    int a2 = hasA ? min(eiA + 2, laA) : 0;
    int a3 = hasA ? min(eiA + 3, laA) : 0;
    int b0 = hasB ? eiB : 0;
    int b1i = hasB ? min(eiB + 1, laB) : 0;
    int b2i = hasB ? min(eiB + 2, laB) : 0;
    int b3 = hasB ? min(eiB + 3, laB) : 0;
    int gA0 = tgt_list[a0], gA1 = tgt_list[a1], gA2 = tgt_list[a2], gA3 = tgt_list[a3];
    int gB0 = tgt_list[b0], gB1 = tgt_list[b1i], gB2 = tgt_list[b2i], gB3 = tgt_list[b3];
    short8v vA0 = *(const short8v*)(U + (size_t)gA0 * 256 + c8);
    short8v vA1 = *(const short8v*)(U + (size_t)gA1 * 256 + c8);
    short8v vA2 = *(const short8v*)(U + (size_t)gA2 * 256 + c8);
    short8v vA3 = *(const short8v*)(U + (size_t)gA3 * 256 + c8);
    short8v vB0 = *(const short8v*)(U + (size_t)gB0 * 256 + c8);
    short8v vB1 = *(const short8v*)(U + (size_t)gB1 * 256 + c8);
    short8v vB2 = *(const short8v*)(U + (size_t)gB2 * 256 + c8);
    short8v vB3 = *(const short8v*)(U + (size_t)gB3 * 256 + c8);
    float mA0 = hasA ? 1.f : 0.f;
    float mA1 = (hasA && eiA + 1 <= laA) ? 1.f : 0.f;
    float mA2 = (hasA && eiA + 2 <= laA) ? 1.f : 0.f;
    float mA3 = (hasA && eiA + 3 <= laA) ? 1.f : 0.f;
    float mB0 = hasB ? 1.f : 0.f;
    float mB1 = (hasB && eiB + 1 <= laB) ? 1.f : 0.f;
    float mB2 = (hasB && eiB + 2 <= laB) ? 1.f : 0.f;
    float mB3 = (hasB && eiB + 3 <= laB) ? 1.f : 0.f;
#pragma unroll
    for (int j = 0; j < 8; ++j) {
      sA[j] += mA0 * fmaxf(uA[j] - bf2f((unsigned short)vA0[j]), 0.f)
             + mA1 * fmaxf(uA[j] - bf2f((unsigned short)vA1[j]), 0.f)
             + mA2 * fmaxf(uA[j] - bf2f((unsigned short)vA2[j]), 0.f)
             + mA3 * fmaxf(uA[j] - bf2f((unsigned short)vA3[j]), 0.f);
      sB[j] += mB0 * fmaxf(uB[j] - bf2f((unsigned short)vB0[j]), 0.f)
             + mB1 * fmaxf(uB[j] - bf2f((unsigned short)vB1[j]), 0.f)
             + mB2 * fmaxf(uB[j] - bf2f((unsigned short)vB2[j]), 0.f)
             + mB3 * fmaxf(uB[j] - bf2f((unsigned short)vB3[j]), 0.f);
    }
    if (hasA) eiA += 4;
    if (hasB) eiB += 4;
  }
  short8v hva, hvb;
#pragma unroll
  for (int j = 0; j < 8; ++j) { hva[j] = (short)f2bf(sA[j]); hvb[j] = (short)f2bf(sB[j]); }
  *(short8v*)(sum_h + (size_t)tA * 256 + c8) = hva;
  if (hasRowB) *(short8v*)(sum_h + (size_t)tB * 256 + c8) = hvb;
}

// ------- out = sum_h @ W2 + count*b2: N-split halves, 512 thr, B-half (64KB) ------
// ------- in LDS (swizzled), full 8-deep A prefetch, zero barriers.          ------
__launch_bounds__(512, 4)
__global__ void out_gemm_kernel(const unsigned short* __restrict__ sum_h,
                                const unsigned short* __restrict__ W2T,
                                const int* __restrict__ count,
                                const float* __restrict__ b2,
                                float* __restrict__ out, int T) {
  __shared__ alignas(16) unsigned short Bl[32768];  // 128 rows x 256 shorts = 64 KB
  int tid = threadIdx.x;
  int half = blockIdx.x & 1;
  int nbase = half * 128;
#pragma unroll
  for (int j = 0; j < 8; ++j) {
    int idx = tid + j * 512;
    int n = idx >> 5, c = idx & 31;  // n = local row 0..127
    int pc = c ^ (n & 7);
    short8v v = *(const short8v*)(W2T + (size_t)(nbase + n) * 256 + c * 8);
    *(short8v*)(&Bl[n * 256 + pc * 8]) = v;
  }
  __syncthreads();
  int wid = tid >> 6, lane = tid & 63;
  int l15 = lane & 15, lhi = lane >> 4;
  int r7 = l15 & 7;
  const unsigned short* lane_b = &Bl[l15 * 256];
  int strip = (blockIdx.x >> 1) * 8 + wid;
  if (strip * 16 >= T) return;
  int row = strip * 16 + l15;
  const unsigned short* arow = sum_h + (size_t)row * 256 + 8 * lhi;
  short8v pa[8];
#pragma unroll
  for (int k = 0; k < 8; ++k) pa[k] = *(const short8v*)(arow + k * 32);
  float b2r[8];
#pragma unroll
  for (int nf = 0; nf < 8; ++nf) b2r[nf] = b2[nbase + nf * 16 + l15];
  f32x4v acc[8] = {};
#pragma unroll
  for (int kk = 0; kk < 8; ++kk) {
    short8v av = pa[kk];
    int pc = (kk * 4 + lhi) ^ r7;
    const unsigned short* bptr = lane_b + pc * 8;
#pragma unroll
    for (int nf = 0; nf < 8; ++nf) {
      short8v bv = *(const short8v*)(bptr + nf * 4096);  // 16 rows * 256
      acc[nf] = __builtin_amdgcn_mfma_f32_16x16x32_bf16(av, bv, acc[nf], 0, 0, 0);
    }
  }
#pragma unroll
  for (int i = 0; i < 4; ++i) {
    int m = strip * 16 + 4 * lhi + i;
    float cnt = (float)count[m];
    float* orow = out + (size_t)m * 256 + nbase + l15;
#pragma unroll
    for (int nf = 0; nf < 8; ++nf)
      orow[nf * 16] = acc[nf][i] + cnt * b2r[nf];
  }
}

extern "C" void kernel_launch(void* const* d_in, const int* in_sizes, int n_in,
                              void* d_out, int out_size, void* d_ws, size_t ws_size,
                              hipStream_t stream) {
  const float* x = (const float*)d_in[0];
  const float* points = (const float*)d_in[1];
  const int* triangles = (const int*)d_in[2];
  const int* te = (const int*)d_in[3];
  const float* W1 = (const float*)d_in[4];
  const float* b1 = (const float*)d_in[5];
  const float* W2 = (const float*)d_in[6];
  const float* b2 = (const float*)d_in[7];
  float* out = (float*)d_out;
  int T = in_sizes[0] / 256;
  int E = in_sizes[3] / 2;

  char* ws = (char*)d_ws;
  size_t off = 0;
  auto alloc = [&](size_t bytes) {
    void* p = ws + off;
    off = (off + bytes + 255) & ~(size_t)255;
    return p;
  };
  unsigned short* U     = (unsigned short*)alloc((size_t)T * 256 * 2);
  float*          geo12 = (float*)alloc(((size_t)T * 12 + 16) * 4);
  unsigned short* W1fT  = (unsigned short*)alloc((size_t)256 * 288 * 2);
  unsigned short* W2T   = (unsigned short*)alloc((size_t)256 * 256 * 2);
  int* count   = (int*)alloc((size_t)(T + 4) * 4);
  int* offsets = (int*)alloc((size_t)(T + 1) * 4);
  int* cursor  = (int*)alloc((size_t)T * 4);
  int* tgtl    = (int*)alloc((size_t)E * 4);
  int* incl    = (int*)alloc((size_t)T * 4);
  int* bsum    = (int*)alloc(256 * 4);
  int* bbase   = (int*)alloc(256 * 4);
  unsigned short* sum_h = (unsigned short*)alloc((size_t)T * 256 * 2);
  if (off > ws_size) return;

  int nb1 = (T + 1023) / 1024;
  int nstrips = (T + 15) / 16;
  int nsblk = (nstrips + 7) / 8;
  zero_kernel<<<200, 256, 0, stream>>>(count, (T + 3) / 4);
  {
    int mx = max(E, max(T, 256 * 288));
    setup_kernel<<<(mx + 255) / 256, 256, 0, stream>>>(W1, W2, points, triangles, te,
                                                       W1fT, W2T, geo12, count, T, E);
  }
  scan1_kernel<<<nb1, 256, 0, stream>>>(count, incl, bsum, T);
  scan2_kernel<<<1, 256, 0, stream>>>(bsum, bbase, nb1);
  scan3_kernel<<<nb1, 256, 0, stream>>>(count, incl, bbase, offsets, cursor, T);
  fill_kernel<<<(E + 255) / 256, 256, 0, stream>>>(te, cursor, tgtl, E);
  ugemm_kernel<<<nsblk * 2, 512, 0, stream>>>(x, geo12, W1fT, U, T);
  {
    int half = (T + 1) >> 1;
    gather_kernel<<<(half * 32 + 255) / 256, 256, 0, stream>>>(U, offsets, tgtl, b1, sum_h, T);
  }
  out_gemm_kernel<<<nsblk * 2, 512, 0, stream>>>(sum_h, W2T, count, b2, out, T);
}

// Round 16
// 331.278 us; speedup vs baseline: 1.0410x; 1.0410x over previous
//
#include <hip/hip_runtime.h>
#include <stdint.h>

typedef float f32x4v __attribute__((ext_vector_type(4)));
typedef short short8v __attribute__((ext_vector_type(8)));

__device__ __forceinline__ float bf2f(unsigned short u) {
  union { uint32_t i; float f; } v; v.i = ((uint32_t)u) << 16; return v.f;
}
__device__ __forceinline__ unsigned short f2bf(float f) {
  union { float f; uint32_t i; } v; v.f = f;
  uint32_t x = v.i;
  uint32_t r = (x + 0x7FFFu + ((x >> 16) & 1u)) >> 16;
  return (unsigned short)r;
}
__device__ __forceinline__ short8v cvt8(float4 a, float4 b) {
  short8v v;
  v[0] = (short)f2bf(a.x); v[1] = (short)f2bf(a.y);
  v[2] = (short)f2bf(a.z); v[3] = (short)f2bf(a.w);
  v[4] = (short)f2bf(b.x); v[5] = (short)f2bf(b.y);
  v[6] = (short)f2bf(b.z); v[7] = (short)f2bf(b.w);
  return v;
}

// ---------------- zero count ----------------
__global__ void zero_kernel(int* __restrict__ p, int n4) {
  int i = blockIdx.x * blockDim.x + threadIdx.x;
  int stride = gridDim.x * blockDim.x;
  for (; i < n4; i += stride) ((int4*)p)[i] = make_int4(0, 0, 0, 0);
}

// ---------------- setup: prep weights + geometry + edge counts ----------------
__global__ void setup_kernel(const float* __restrict__ W1, const float* __restrict__ W2,
                             const float* __restrict__ points, const int* __restrict__ tri,
                             const int* __restrict__ te,
                             unsigned short* __restrict__ W1fT, unsigned short* __restrict__ W2T,
                             float* __restrict__ geo12, int* __restrict__ count,
                             int T, int E) {
  int i = blockIdx.x * blockDim.x + threadIdx.x;
  if (i < 256 * 288) {
    int n = i / 288, k = i % 288;
    float v = 0.f;
    if (k < 256) v = W1[(9 + k) * 256 + n];
    else if (k < 265) v = W1[(k - 256) * 256 + n];
    W1fT[i] = f2bf(v);
  }
  if (i < 256 * 256) {
    int n = i >> 8, k = i & 255;
    W2T[i] = f2bf(W2[k * 256 + n]);
  }
  if (i < T) {
    int t = i;
    int i0 = tri[3 * t], i1 = tri[3 * t + 1], i2 = tri[3 * t + 2];
    float g[12];
#pragma unroll
    for (int c = 0; c < 3; ++c) {
      float p0 = points[i0 * 3 + c], p1 = points[i1 * 3 + c], p2 = points[i2 * 3 + c];
      float e0 = p0 - p1, e1 = p0 - p2, e2 = p1 - p2;
      float mx = fmaxf(e0, fmaxf(e1, e2));
      float mn = fminf(e0, fminf(e1, e2));
      float bc = (p0 + p1 + p2) * (1.0f / 3.0f);
      g[c] = mn; g[3 + c] = mx; g[6 + c] = bc;
    }
    g[9] = 0.f; g[10] = 0.f; g[11] = 0.f;
    float4* o = (float4*)(geo12 + (size_t)t * 12);
    o[0] = make_float4(g[0], g[1], g[2], g[3]);
    o[1] = make_float4(g[4], g[5], g[6], g[7]);
    o[2] = make_float4(g[8], g[9], g[10], g[11]);
  }
  if (i < E) atomicAdd(&count[te[i]], 1);
}

// ---------------- CSR scan ----------------
__global__ void scan1_kernel(const int* __restrict__ count, int* __restrict__ incl,
                             int* __restrict__ blocksum, int T) {
  __shared__ int wsums[4];
  int tid = threadIdx.x, wave = tid >> 6, lane = tid & 63;
  int idx0 = blockIdx.x * 1024 + tid * 4;
  int c0 = 0, c1 = 0, c2 = 0, c3 = 0;
  if (idx0 + 3 < T) {
    int4 v = *(const int4*)(count + idx0);
    c0 = v.x; c1 = v.y; c2 = v.z; c3 = v.w;
  } else {
    if (idx0 < T) c0 = count[idx0];
    if (idx0 + 1 < T) c1 = count[idx0 + 1];
    if (idx0 + 2 < T) c2 = count[idx0 + 2];
  }
  int s = c0 + c1 + c2 + c3;
  int inclv = s;
#pragma unroll
  for (int off = 1; off < 64; off <<= 1) {
    int n = __shfl_up(inclv, off);
    if (lane >= off) inclv += n;
  }
  if (lane == 63) wsums[wave] = inclv;
  __syncthreads();
  int wbase = 0;
#pragma unroll
  for (int w = 0; w < 4; ++w) if (w < wave) wbase += wsums[w];
  int base = wbase + inclv - s;
  int e0 = base + c0, e1 = e0 + c1, e2 = e1 + c2, e3 = e2 + c3;
  if (idx0 < T) incl[idx0] = e0;
  if (idx0 + 1 < T) incl[idx0 + 1] = e1;
  if (idx0 + 2 < T) incl[idx0 + 2] = e2;
  if (idx0 + 3 < T) incl[idx0 + 3] = e3;
  if (tid == 255) blocksum[blockIdx.x] = wbase + inclv;
}

__global__ void scan2_kernel(const int* __restrict__ blocksum, int* __restrict__ blockbase, int nb) {
  __shared__ int wsums[4];
  int tid = threadIdx.x, wave = tid >> 6, lane = tid & 63;
  int v = (tid < nb) ? blocksum[tid] : 0;
  int inclv = v;
#pragma unroll
  for (int off = 1; off < 64; off <<= 1) {
    int n = __shfl_up(inclv, off);
    if (lane >= off) inclv += n;
  }
  if (lane == 63) wsums[wave] = inclv;
  __syncthreads();
  int wbase = 0;
#pragma unroll
  for (int w = 0; w < 4; ++w) if (w < wave) wbase += wsums[w];
  if (tid < nb) blockbase[tid] = wbase + inclv - v;
}

__global__ void scan3_kernel(const int* __restrict__ count, const int* __restrict__ incl,
                             const int* __restrict__ blockbase, int* __restrict__ offsets,
                             int* __restrict__ cursor, int T) {
  int idx = blockIdx.x * 1024 + threadIdx.x * 4;
  int bb = blockbase[blockIdx.x];
#pragma unroll
  for (int j = 0; j < 4; ++j) {
    int i = idx + j;
    if (i < T) {
      int o = incl[i] + bb;
      offsets[i + 1] = o;
      cursor[i] = o - count[i];
    }
  }
  if (blockIdx.x == 0 && threadIdx.x == 0) offsets[0] = 0;
}

__global__ void fill_kernel(const int* __restrict__ te, int* __restrict__ cursor,
                            int* __restrict__ tgt_list, int E) {
  int e = blockIdx.x * blockDim.x + threadIdx.x;
  if (e < E) {
    int s = te[e];
    int pos = atomicAdd(&cursor[s], 1);
    tgt_list[pos] = te[E + e];
  }
}

// ------- U = [x | geo] @ W1: exact grid, whole B in LDS (XOR-swizzled), ------
// ------- ring-4 A-prefetch, ZERO barriers in K-loop. (r14 best: ~118us) ------
__launch_bounds__(1024, 4)
__global__ void ugemm_kernel(const float* __restrict__ x, const float* __restrict__ geo12,
                             const unsigned short* __restrict__ W1fT,
                             unsigned short* __restrict__ U, int T) {
  __shared__ alignas(16) unsigned short Bl[73728];  // 256 x 288 shorts = 144 KB
  int tid = threadIdx.x;
#pragma unroll
  for (int j = 0; j < 9; ++j) {
    int idx = tid + j * 1024;
    int n = idx / 36, c = idx % 36;
    int pc = (c < 32) ? (c ^ (n & 7)) : (32 + ((c - 32) ^ (n & 3)));
    short8v v = *(const short8v*)(W1fT + (size_t)n * 288 + c * 8);
    *(short8v*)(&Bl[n * 288 + pc * 8]) = v;
  }
  __syncthreads();
  int wid = tid >> 6, lane = tid & 63;
  int l15 = lane & 15, lhi = lane >> 4;
  int r7 = l15 & 7, r3 = l15 & 3;
  const unsigned short* lane_b = &Bl[l15 * 288];
  int strip = blockIdx.x * 16 + wid;
  if (strip * 16 >= T) return;
  int row = strip * 16 + l15;
  const float* xrow = x + (size_t)row * 256 + 8 * lhi;
  float4 ga = make_float4(0, 0, 0, 0), gb = make_float4(0, 0, 0, 0);
  if (lhi < 2) {
    const float* gp = geo12 + (size_t)row * 12 + lhi * 8;
    ga = *(const float4*)gp;
    gb = *(const float4*)(gp + 4);
  }
  float4 pa[4], pb[4];
#pragma unroll
  for (int k = 0; k < 4; ++k) {
    pa[k] = *(const float4*)(xrow + k * 32);
    pb[k] = *(const float4*)(xrow + k * 32 + 4);
  }
  f32x4v acc[16] = {};
#pragma unroll
  for (int kk = 0; kk < 8; ++kk) {
    float4 ca = pa[kk & 3], cb = pb[kk & 3];
    if (kk < 4) {
      pa[kk & 3] = *(const float4*)(xrow + (kk + 4) * 32);
      pb[kk & 3] = *(const float4*)(xrow + (kk + 4) * 32 + 4);
    }
    short8v av = cvt8(ca, cb);
    int pc = (kk * 4 + lhi) ^ r7;
    const unsigned short* bptr = lane_b + pc * 8;
#pragma unroll
    for (int nf = 0; nf < 16; ++nf) {
      short8v bv = *(const short8v*)(bptr + nf * 4608);
      acc[nf] = __builtin_amdgcn_mfma_f32_16x16x32_bf16(av, bv, acc[nf], 0, 0, 0);
    }
  }
  {  // geo tail k=256..287
    short8v av = cvt8(ga, gb);
    int pc = 32 + (lhi ^ r3);
    const unsigned short* bptr = lane_b + pc * 8;
#pragma unroll
    for (int nf = 0; nf < 16; ++nf) {
      short8v bv = *(const short8v*)(bptr + nf * 4608);
      acc[nf] = __builtin_amdgcn_mfma_f32_16x16x32_bf16(av, bv, acc[nf], 0, 0, 0);
    }
  }
#pragma unroll
  for (int i = 0; i < 4; ++i) {
    int m = strip * 16 + 4 * lhi + i;
    unsigned short* urow = U + (size_t)m * 256 + l15;
#pragma unroll
    for (int nf = 0; nf < 16; ++nf)
      urow[nf * 16] = f2bf(acc[nf][i]);
  }
}

// ---------------- gather: sum_h[t] = sum_e relu(U[t]+b1-U[tgt]) ----------------
// (256,4): 44 VGPR, 8 in-flight 16B loads. Do NOT cap below 4 waves/EU (r3/r13).
__launch_bounds__(256, 4)
__global__ void gather_kernel(const unsigned short* __restrict__ U,
                              const int* __restrict__ offsets,
                              const int* __restrict__ tgt_list,
                              const float* __restrict__ b1,
                              unsigned short* __restrict__ sum_h, int T) {
  int gid = blockIdx.x * blockDim.x + threadIdx.x;
  int half = (T + 1) >> 1;
  int pair = gid >> 5;
  if (pair >= half) return;
  int c8 = (gid & 31) * 8;
  int tA = pair, tB = pair + half;
  bool hasRowB = tB < T;
  int begA = offsets[tA], endA = offsets[tA + 1];
  int begB = hasRowB ? offsets[tB] : 0, endB = hasRowB ? offsets[tB + 1] : 0;
  float b1r[8];
  {
    float4 a = *(const float4*)(b1 + c8);
    float4 b = *(const float4*)(b1 + c8 + 4);
    b1r[0] = a.x; b1r[1] = a.y; b1r[2] = a.z; b1r[3] = a.w;
    b1r[4] = b.x; b1r[5] = b.y; b1r[6] = b.z; b1r[7] = b.w;
  }
  short8v uva = *(const short8v*)(U + (size_t)tA * 256 + c8);
  short8v uvb = *(const short8v*)(U + (size_t)(hasRowB ? tB : tA) * 256 + c8);
  float uA[8], sA[8], uB[8], sB[8];
#pragma unroll
  for (int j = 0; j < 8; ++j) {
    uA[j] = bf2f((unsigned short)uva[j]) + b1r[j]; sA[j] = 0.f;
    uB[j] = bf2f((unsigned short)uvb[j]) + b1r[j]; sB[j] = 0.f;
  }
  int eiA = begA, eiB = begB;
  while (eiA < endA || eiB < endB) {
    bool hasA = eiA < endA, hasB = eiB < endB;
    int laA = hasA ? endA - 1 : 0;
    int laB = hasB ? endB - 1 : 0;
    int a0 = hasA ? eiA : 0;
    int a1 = hasA ? min(eiA + 1, laA) : 0;
    int a2 = hasA ? min(eiA + 2, laA) : 0;
    int a3 = hasA ? min(eiA + 3, laA) : 0;
    int b0 = hasB ? eiB : 0;
    int b1i = hasB ? min(eiB + 1, laB) : 0;
    int b2i = hasB ? min(eiB + 2, laB) : 0;
    int b3 = hasB ? min(eiB + 3, laB) : 0;
    int gA0 = tgt_list[a0], gA1 = tgt_list[a1], gA2 = tgt_list[a2], gA3 = tgt_list[a3];
    int gB0 = tgt_list[b0], gB1 = tgt_list[b1i], gB2 = tgt_list[b2i], gB3 = tgt_list[b3];
    short8v vA0 = *(const short8v*)(U + (size_t)gA0 * 256 + c8);
    short8v vA1 = *(const short8v*)(U + (size_t)gA1 * 256 + c8);
    short8v vA2 = *(const short8v*)(U + (size_t)gA2 * 256 + c8);
    short8v vA3 = *(const short8v*)(U + (size_t)gA3 * 256 + c8);
    short8v vB0 = *(const short8v*)(U + (size_t)gB0 * 256 + c8);
    short8v vB1 = *(const short8v*)(U + (size_t)gB1 * 256 + c8);
    short8v vB2 = *(const short8v*)(U + (size_t)gB2 * 256 + c8);
    short8v vB3 = *(const short8v*)(U + (size_t)gB3 * 256 + c8);
    float mA0 = hasA ? 1.f : 0.f;
    float mA1 = (hasA && eiA + 1 <= laA) ? 1.f : 0.f;
    float mA2 = (hasA && eiA + 2 <= laA) ? 1.f : 0.f;
    float mA3 = (hasA && eiA + 3 <= laA) ? 1.f : 0.f;
    float mB0 = hasB ? 1.f : 0.f;
    float mB1 = (hasB && eiB + 1 <= laB) ? 1.f : 0.f;
    float mB2 = (hasB && eiB + 2 <= laB) ? 1.f : 0.f;
    float mB3 = (hasB && eiB + 3 <= laB) ? 1.f : 0.f;
#pragma unroll
    for (int j = 0; j < 8; ++j) {
      sA[j] += mA0 * fmaxf(uA[j] - bf2f((unsigned short)vA0[j]), 0.f)
             + mA1 * fmaxf(uA[j] - bf2f((unsigned short)vA1[j]), 0.f)
             + mA2 * fmaxf(uA[j] - bf2f((unsigned short)vA2[j]), 0.f)
             + mA3 * fmaxf(uA[j] - bf2f((unsigned short)vA3[j]), 0.f);
      sB[j] += mB0 * fmaxf(uB[j] - bf2f((unsigned short)vB0[j]), 0.f)
             + mB1 * fmaxf(uB[j] - bf2f((unsigned short)vB1[j]), 0.f)
             + mB2 * fmaxf(uB[j] - bf2f((unsigned short)vB2[j]), 0.f)
             + mB3 * fmaxf(uB[j] - bf2f((unsigned short)vB3[j]), 0.f);
    }
    if (hasA) eiA += 4;
    if (hasB) eiB += 4;
  }
  short8v hva, hvb;
#pragma unroll
  for (int j = 0; j < 8; ++j) { hva[j] = (short)f2bf(sA[j]); hvb[j] = (short)f2bf(sB[j]); }
  *(short8v*)(sum_h + (size_t)tA * 256 + c8) = hva;
  if (hasRowB) *(short8v*)(sum_h + (size_t)tB * 256 + c8) = hvb;
}

// ------- out = sum_h @ W2 + count*b2: exact grid, B in LDS (swizzled), ------
// ------- full 8-deep A prefetch, zero barriers in K-loop.              ------
__launch_bounds__(1024, 4)
__global__ void out_gemm_kernel(const unsigned short* __restrict__ sum_h,
                                const unsigned short* __restrict__ W2T,
                                const int* __restrict__ count,
                                const float* __restrict__ b2,
                                float* __restrict__ out, int T) {
  __shared__ alignas(16) unsigned short Bl[65536];  // 256 x 256 shorts = 128 KB
  int tid = threadIdx.x;
#pragma unroll
  for (int j = 0; j < 8; ++j) {
    int idx = tid + j * 1024;
    int n = idx >> 5, c = idx & 31;
    int pc = c ^ (n & 7);
    short8v v = *(const short8v*)(W2T + (size_t)n * 256 + c * 8);
    *(short8v*)(&Bl[n * 256 + pc * 8]) = v;
  }
  __syncthreads();
  int wid = tid >> 6, lane = tid & 63;
  int l15 = lane & 15, lhi = lane >> 4;
  int r7 = l15 & 7;
  const unsigned short* lane_b = &Bl[l15 * 256];
  int strip = blockIdx.x * 16 + wid;
  if (strip * 16 >= T) return;
  int row = strip * 16 + l15;
  const unsigned short* arow = sum_h + (size_t)row * 256 + 8 * lhi;
  short8v pa[8];
#pragma unroll
  for (int k = 0; k < 8; ++k) pa[k] = *(const short8v*)(arow + k * 32);
  float b2r[16];
#pragma unroll
  for (int nf = 0; nf < 16; ++nf) b2r[nf] = b2[nf * 16 + l15];
  f32x4v acc[16] = {};
#pragma unroll
  for (int kk = 0; kk < 8; ++kk) {
    short8v av = pa[kk];
    int pc = (kk * 4 + lhi) ^ r7;
    const unsigned short* bptr = lane_b + pc * 8;
#pragma unroll
    for (int nf = 0; nf < 16; ++nf) {
      short8v bv = *(const short8v*)(bptr + nf * 4096);
      acc[nf] = __builtin_amdgcn_mfma_f32_16x16x32_bf16(av, bv, acc[nf], 0, 0, 0);
    }
  }
#pragma unroll
  for (int i = 0; i < 4; ++i) {
    int m = strip * 16 + 4 * lhi + i;
    float cnt = (float)count[m];
    float* orow = out + (size_t)m * 256 + l15;
#pragma unroll
    for (int nf = 0; nf < 16; ++nf)
      orow[nf * 16] = acc[nf][i] + cnt * b2r[nf];
  }
}

extern "C" void kernel_launch(void* const* d_in, const int* in_sizes, int n_in,
                              void* d_out, int out_size, void* d_ws, size_t ws_size,
                              hipStream_t stream) {
  const float* x = (const float*)d_in[0];
  const float* points = (const float*)d_in[1];
  const int* triangles = (const int*)d_in[2];
  const int* te = (const int*)d_in[3];
  const float* W1 = (const float*)d_in[4];
  const float* b1 = (const float*)d_in[5];
  const float* W2 = (const float*)d_in[6];
  const float* b2 = (const float*)d_in[7];
  float* out = (float*)d_out;
  int T = in_sizes[0] / 256;
  int E = in_sizes[3] / 2;

  char* ws = (char*)d_ws;
  size_t off = 0;
  auto alloc = [&](size_t bytes) {
    void* p = ws + off;
    off = (off + bytes + 255) & ~(size_t)255;
    return p;
  };
  unsigned short* U     = (unsigned short*)alloc((size_t)T * 256 * 2);
  float*          geo12 = (float*)alloc(((size_t)T * 12 + 16) * 4);
  unsigned short* W1fT  = (unsigned short*)alloc((size_t)256 * 288 * 2);
  unsigned short* W2T   = (unsigned short*)alloc((size_t)256 * 256 * 2);
  int* count   = (int*)alloc((size_t)(T + 4) * 4);
  int* offsets = (int*)alloc((size_t)(T + 1) * 4);
  int* cursor  = (int*)alloc((size_t)T * 4);
  int* tgtl    = (int*)alloc((size_t)E * 4);
  int* incl    = (int*)alloc((size_t)T * 4);
  int* bsum    = (int*)alloc(256 * 4);
  int* bbase   = (int*)alloc(256 * 4);
  unsigned short* sum_h = (unsigned short*)alloc((size_t)T * 256 * 2);
  if (off > ws_size) return;

  int nb1 = (T + 1023) / 1024;
  int nstrips = (T + 15) / 16;
  int ngemm = (nstrips + 15) / 16;
  zero_kernel<<<200, 256, 0, stream>>>(count, (T + 3) / 4);
  {
    int mx = max(E, max(T, 256 * 288));
    setup_kernel<<<(mx + 255) / 256, 256, 0, stream>>>(W1, W2, points, triangles, te,
                                                       W1fT, W2T, geo12, count, T, E);
  }
  scan1_kernel<<<nb1, 256, 0, stream>>>(count, incl, bsum, T);
  scan2_kernel<<<1, 256, 0, stream>>>(bsum, bbase, nb1);
  scan3_kernel<<<nb1, 256, 0, stream>>>(count, incl, bbase, offsets, cursor, T);
  fill_kernel<<<(E + 255) / 256, 256, 0, stream>>>(te, cursor, tgtl, E);
  ugemm_kernel<<<ngemm, 1024, 0, stream>>>(x, geo12, W1fT, U, T);
  {
    int half = (T + 1) >> 1;
    gather_kernel<<<(half * 32 + 255) / 256, 256, 0, stream>>>(U, offsets, tgtl, b1, sum_h, T);
  }
  out_gemm_kernel<<<ngemm, 1024, 0, stream>>>(sum_h, W2T, count, b2, out, T);
}